// Round 10
// baseline (805.049 us; speedup 1.0000x reference)
//
#include <hip/hip_runtime.h>
#include <cstdint>
#include <cstddef>

// ---------------------------------------------------------------------------
// Transformer block, B=2 T=2048 C=2048 NH=16 NKV=4 HD=128 DFF=8192, gfx950.
// R14: (1) gemm256: cross-tile read-ahead of ONLY R1 (afl+bl, 12 reads),
// issued after the end-of-tile vmcnt(4)+barrier (t+1 proven in LDS) and
// before C4 -> R1' drains under C4+loop+lgkm12 instead of stalling C1 at
// tile top (the ~750cyc MFMA-idle window); C4's LDS-idle window now carries
// reads. WAR-safe: afl dead after C2, bl after C3. lgkm counts unchanged
// (per-wave DS order R1',R2,R3 -> 12/8/0). R10's failure mode (mid-tile
// vmcnt(0) + thin cover for ALL reads) avoided. (2) attn: defer-max
// (T13, THR=8, wave-uniform __all) skips the O-rescale when max is stable.
// R13 supertile swizzle, R11 attn overlap, R12 prep_all kept.
// ---------------------------------------------------------------------------

#define B_    2
#define T_    2048
#define C_    2048
#define NH_   16
#define NKV_  4
#define HD_   128
#define DFF_  8192
#define EPS_  1.1920928955078125e-07f   // jnp.finfo(float32).eps

typedef short          bf16x8 __attribute__((ext_vector_type(8)));
typedef float          f32x4  __attribute__((ext_vector_type(4)));
typedef unsigned short u16;
typedef unsigned short u16x8  __attribute__((ext_vector_type(8)));
typedef unsigned short u16x4  __attribute__((ext_vector_type(4)));

__device__ __forceinline__ u16 f2bf(float f) {
    unsigned u = __float_as_uint(f);
    unsigned r = u + 0x7fffu + ((u >> 16) & 1u);   // RNE; inputs are finite
    return (u16)(r >> 16);
}
__device__ __forceinline__ float bf2f(u16 u) {
    return __uint_as_float((unsigned)u << 16);
}

__device__ __forceinline__ void load_lds16(const void* g, void* l) {
    // 16B per lane, LDS dest = wave-uniform base + lane*16 (guide §5 caveat)
    __builtin_amdgcn_global_load_lds(
        (__attribute__((address_space(1))) void*)(g),
        (__attribute__((address_space(3))) void*)(l), 16, 0, 0);
}

// LDS byte address of a pointer into __shared__
__device__ __forceinline__ unsigned lds_addr(const void* p) {
    return (unsigned)(unsigned long long)(__attribute__((address_space(3))) const void*)p;
}

// ---------------------------------------------------------------------------
// prep_all: (a) 6 weight transposes f32[K][N] -> bf16[N][K] in 32x128 tiles,
// (b) rmsnorm rows of x (blocks >= TRBLKS). One launch, 256 threads.
// ---------------------------------------------------------------------------
struct TD  { const float* src; u16* dst; int K, N, boff; };
struct TD6 { TD t[6]; };

#define TRBLKS_ 10752

__global__ void prep_all(TD6 d, const float* __restrict__ x, u16* __restrict__ hout) {
    __shared__ u16 tile[32][136];          // 8.7 KB; rows 272B (17x16B)
    __shared__ float part[4];
    int bid = blockIdx.x;
    int tid = threadIdx.x;

    if (bid >= TRBLKS_) {                  // ---- rmsnorm branch ----
        int row = bid - TRBLKS_;
        const float4* xr = (const float4*)(x + (size_t)row * C_);
        float4 a = xr[tid];
        float4 b = xr[tid + 256];
        float ss = a.x * a.x + a.y * a.y + a.z * a.z + a.w * a.w
                 + b.x * b.x + b.y * b.y + b.z * b.z + b.w * b.w;
        for (int m = 1; m < 64; m <<= 1) ss += __shfl_xor(ss, m, 64);
        if ((tid & 63) == 0) part[tid >> 6] = ss;
        __syncthreads();
        float tot = part[0] + part[1] + part[2] + part[3];
        float sc = rsqrtf(tot * (1.0f / C_) + EPS_);
        u16x4 o1, o2;
        o1[0] = f2bf(a.x * sc); o1[1] = f2bf(a.y * sc); o1[2] = f2bf(a.z * sc); o1[3] = f2bf(a.w * sc);
        o2[0] = f2bf(b.x * sc); o2[1] = f2bf(b.y * sc); o2[2] = f2bf(b.z * sc); o2[3] = f2bf(b.w * sc);
        u16x4* orow = (u16x4*)(hout + (size_t)row * C_);
        orow[tid]       = o1;
        orow[tid + 256] = o2;
        return;
    }

    // ---- transpose branch ----
    int di = 0;
    for (int i = 5; i > 0; --i) if (bid >= d.t[i].boff) { di = i; break; }
    const float* src = d.t[di].src;
    u16* dst = d.t[di].dst;
    int K = d.t[di].K, N = d.t[di].N;
    int lb = bid - d.t[di].boff;
    int nx = N >> 5;                       // N/32 tiles along n
    int n0 = (lb % nx) * 32;
    int k0 = (lb / nx) * 128;

    int kr = tid >> 3;                     // 0..31
    int nc = (tid & 7) * 4;                // 0,4,...,28
    for (int r = 0; r < 4; ++r) {
        int kk = kr + r * 32;              // 0..127
        float4 v = *(const float4*)&src[(size_t)(k0 + kk) * N + n0 + nc];
        tile[nc + 0][kk] = f2bf(v.x);
        tile[nc + 1][kk] = f2bf(v.y);
        tile[nc + 2][kk] = f2bf(v.z);
        tile[nc + 3][kk] = f2bf(v.w);
    }
    __syncthreads();
    int nL = tid >> 4;                     // 0..15
    int kc = (tid & 15) * 8;               // 0..120
    for (int w2 = 0; w2 < 2; ++w2) {
        int n = nL + w2 * 16;
        u16x8 o = *(const u16x8*)&tile[n][kc];
        *(u16x8*)&dst[(size_t)(n0 + n) * K + k0 + kc] = o;
    }
}

// ---------------------------------------------------------------------------
// rope_tv: merged RoPE+qk-rmsnorm AND V transpose in one launch.
// ---------------------------------------------------------------------------
#define TVB_ 1024

__global__ void rope_tv(const float* __restrict__ Xq, const float* __restrict__ Xk,
                        const float* __restrict__ cosb, const float* __restrict__ sinb,
                        u16* __restrict__ Oq, u16* __restrict__ Ok,
                        const u16* __restrict__ vb, u16* __restrict__ Vt) {
    int bid = blockIdx.x;
    if (bid < TVB_) {                      // ---- V transpose branch ----
        int bxx  = bid & 127;
        int kvh  = (bid >> 7) & 3;
        int b    = bid >> 9;
        int dblk = bxx & 1;
        int t0   = (bxx >> 1) * 32;
        int dl   = threadIdx.x & 63;
        int tc   = threadIdx.x >> 6;       // 0..3
        int d    = dblk * 64 + dl;
        u16x8 v8;
        for (int j = 0; j < 8; ++j) {
            int t = t0 + tc * 8 + j;
            v8[j] = vb[((size_t)(b * T_ + t) * NKV_ + kvh) * HD_ + d];
        }
        *(u16x8*)(Vt + ((size_t)((b * NKV_ + kvh) * HD_ + d)) * T_ + t0 + tc * 8) = v8;
        return;
    }
    int gw   = (int)(((bid - TVB_) * blockDim.x + threadIdx.x) >> 6);
    int lane = threadIdx.x & 63;
    const float* X; u16* O; int t;
    if (gw < B_ * T_ * NH_) {
        X = Xq + (size_t)gw * HD_;  O = Oq + (size_t)gw * HD_;  t = (gw / NH_) % T_;
    } else {
        int w2 = gw - B_ * T_ * NH_;
        X = Xk + (size_t)w2 * HD_;  O = Ok + (size_t)w2 * HD_;  t = (w2 / NKV_) % T_;
    }
    float x1 = X[lane];
    float x2 = X[64 + lane];
    float c  = cosb[t * 64 + lane];
    float sn = sinb[t * 64 + lane];
    float r1 = x1 * c + x2 * sn;
    float r2 = x2 * c - x1 * sn;
    float ss = r1 * r1 + r2 * r2;
    for (int m = 1; m < 64; m <<= 1) ss += __shfl_xor(ss, m, 64);
    float sc = rsqrtf(ss * (1.0f / HD_) + EPS_);
    O[lane]      = f2bf(r1 * sc);
    O[64 + lane] = f2bf(r2 * sc);
}

// ---------------------------------------------------------------------------
// Fused split-K reduce + residual + RMSNorm:
//   x2 = x + p0 + p1 (bf16 partials);  hout = rmsnorm(x2) bf16
// NOTE: p0 may alias hout (read-before-write, same indices).
// ---------------------------------------------------------------------------
__global__ void reduce_rms(const float* __restrict__ x, const u16* __restrict__ p0,
                           const u16* __restrict__ p1, float* __restrict__ x2,
                           u16* __restrict__ hout) {
    int row = blockIdx.x;
    const float4* xr = (const float4*)(x + (size_t)row * C_);
    const u16x4* a0 = (const u16x4*)(p0 + (size_t)row * C_);
    const u16x4* a1 = (const u16x4*)(p1 + (size_t)row * C_);
    float4 v[2];
    float ss = 0.f;
    for (int h = 0; h < 2; ++h) {
        int idx = threadIdx.x + h * 256;
        float4 xv = xr[idx];
        u16x4 b0 = a0[idx], b1 = a1[idx];
        v[h].x = xv.x + bf2f(b0[0]) + bf2f(b1[0]);
        v[h].y = xv.y + bf2f(b0[1]) + bf2f(b1[1]);
        v[h].z = xv.z + bf2f(b0[2]) + bf2f(b1[2]);
        v[h].w = xv.w + bf2f(b0[3]) + bf2f(b1[3]);
        ss += v[h].x * v[h].x + v[h].y * v[h].y + v[h].z * v[h].z + v[h].w * v[h].w;
    }
    for (int m = 1; m < 64; m <<= 1) ss += __shfl_xor(ss, m, 64);
    __shared__ float part[4];
    if ((threadIdx.x & 63) == 0) part[threadIdx.x >> 6] = ss;
    __syncthreads();
    float tot = part[0] + part[1] + part[2] + part[3];
    float sc = rsqrtf(tot * (1.0f / C_) + EPS_);
    float4* x2r = (float4*)(x2 + (size_t)row * C_);
    u16x4* hr   = (u16x4*)(hout + (size_t)row * C_);
    for (int h = 0; h < 2; ++h) {
        int idx = threadIdx.x + h * 256;
        x2r[idx] = v[h];
        u16x4 o;
        o[0] = f2bf(v[h].x * sc); o[1] = f2bf(v[h].y * sc);
        o[2] = f2bf(v[h].z * sc); o[3] = f2bf(v[h].w * sc);
        hr[idx] = o;
    }
}

// ---------------------------------------------------------------------------
// Final split-K reduce + residual: out = x2 + p0 + p1  (elementwise, f32)
// ---------------------------------------------------------------------------
__global__ void reduce_out(const float* __restrict__ x2, const u16* __restrict__ p0,
                           const u16* __restrict__ p1, float* __restrict__ out) {
    size_t i = (size_t)blockIdx.x * 256 + threadIdx.x;
    float4 xv = ((const float4*)x2)[i];
    u16x4 b0 = ((const u16x4*)p0)[i];
    u16x4 b1 = ((const u16x4*)p1)[i];
    float4 o;
    o.x = xv.x + bf2f(b0[0]) + bf2f(b1[0]);
    o.y = xv.y + bf2f(b0[1]) + bf2f(b1[1]);
    o.z = xv.z + bf2f(b0[2]) + bf2f(b1[2]);
    o.w = xv.w + bf2f(b0[3]) + bf2f(b1[3]);
    ((float4*)out)[i] = o;
}

// ---------------------------------------------------------------------------
// 256x256 GEMM, counted-lgkm + cross-tile R1 read-ahead (R14).
// Steady state, tile t (buf=t&1; R1=afl+bl of t already in flight):
//   top: issue R2(bh,4), R3(afh,8); stage A1B1(t+1)->buf^1
//   LGKMN(12) [R1 done]  -> C1 = MFMA(afl,bl)
//   LGKMN(8)  [R2 done]  -> C2 = MFMA(afl,bh)
//   LGKMN(0) + BARRIER   -> stage B0A0(t+2)->buf (restage safe)
//   C3 = MFMA(afh,bl)
//   vmcnt(4) [t+1 fully in LDS] + BARRIER
//   issue R1'(t+1: afl,bl from buf^1)   [WAR-safe: afl dead after C2,
//   C4 = MFMA(afh,bh)                     bl dead after C3]
// vmem ring identical to R9 (audited); lgkm counts 12/8/0 valid (per-wave
// DS order R1',R2,R3). EPI: 2=relu^2, 4=qkv routing, 5=split-K partial.
// ---------------------------------------------------------------------------

#define BARRIER() do { __builtin_amdgcn_s_barrier();                     \
                       asm volatile("" ::: "memory"); } while (0)
#define LGKMN(N)  do { asm volatile("s_waitcnt lgkmcnt(" #N ")" ::: "memory");\
                       __builtin_amdgcn_sched_barrier(0); } while (0)

#define DSR(dst, base, lit)                                              \
    asm volatile("ds_read_b128 %0, %1 offset:" lit : "=v"(dst) : "v"(base))

#define READ_AFL(a0, a1) do {                                            \
    DSR(afl[0][0], a0, "0");     DSR(afl[0][1], a1, "0");                \
    DSR(afl[1][0], a0, "2048");  DSR(afl[1][1], a1, "2048");             \
    DSR(afl[2][0], a0, "4096");  DSR(afl[2][1], a1, "4096");             \
    DSR(afl[3][0], a0, "6144");  DSR(afl[3][1], a1, "6144"); } while (0)

#define READ_AFH(a0, a1) do {                                            \
    DSR(afh[0][0], a0, "8192");  DSR(afh[0][1], a1, "8192");             \
    DSR(afh[1][0], a0, "10240"); DSR(afh[1][1], a1, "10240");            \
    DSR(afh[2][0], a0, "12288"); DSR(afh[2][1], a1, "12288");            \
    DSR(afh[3][0], a0, "14336"); DSR(afh[3][1], a1, "14336"); } while (0)

#define READ_BL(b0, b1) do {                                             \
    DSR(bl[0][0], b0, "0");     DSR(bl[0][1], b1, "0");                  \
    DSR(bl[1][0], b0, "2048");  DSR(bl[1][1], b1, "2048"); } while (0)

#define READ_BH(b0, b1) do {                                             \
    DSR(bh[0][0], b0, "4096");  DSR(bh[0][1], b1, "4096");               \
    DSR(bh[1][0], b0, "6144");  DSR(bh[1][1], b1, "6144"); } while (0)

#define MFMA_BLK(AF, BF, MB, NB)                                             \
    _Pragma("unroll")                                                        \
    for (int ks = 0; ks < 2; ++ks)                                           \
        _Pragma("unroll")                                                    \
        for (int mi = 0; mi < 4; ++mi)                                       \
            _Pragma("unroll")                                                \
            for (int ni = 0; ni < 2; ++ni)                                   \
                acc[MB + mi][NB + ni] =                                      \
                    __builtin_amdgcn_mfma_f32_16x16x32_bf16(                 \
                        AF[mi][ks], BF[ni][ks], acc[MB + mi][NB + ni], 0, 0, 0);

template <int EPI>
__launch_bounds__(512, 1)
__global__ void gemm256(const u16* __restrict__ A, const u16* __restrict__ Bt,
                        void* __restrict__ out, void* __restrict__ out2,
                        void* __restrict__ out3, int M, int N, int K, int Ks) {
    // 128 KiB static LDS (gfx950 limit 160 KiB/WG)
    __shared__ __attribute__((aligned(16))) u16 sh[65536];

    int tid  = threadIdx.x;
    int l    = tid & 63;
    int w    = tid >> 6;          // 0..7
    int l16  = l & 15;
    int quad = l >> 4;            // 0..3
    int sw   = l & 7;             // read-side swizzle key
    int wm   = w >> 2, wn = w & 3;

    // T1 + R13: XCD-contiguous chunks, square supertile order inside.
    int nwg = gridDim.x * gridDim.y;
    int id  = blockIdx.y * gridDim.x + blockIdx.x;
    int cpx = nwg >> 3;
    int sid = (id & 7) * cpx + (id >> 3);
    int GN   = (cpx >= 64) ? 8 : 4;
    int span = gridDim.y * GN;
    int bnb  = sid / span;
    int r0   = sid % span;
    int bm   = r0 / GN;
    int bn   = bnb * GN + (r0 % GN);

    size_t koff = (size_t)blockIdx.z * K;
    int nt = K >> 6;              // all our launches: nt >= 16

    // staging: lane covers LDS row (w*8 + l/8), chunk l%8; source chunk is
    // pre-swizzled so swizzled reads see the right data (rule #21)
    int csrc = ((l & 7) ^ ((l >> 3) & 7)) * 8;
    int srow = w * 8 + (l >> 3);
    const u16* Ast = A  + (size_t)(bm * 256 + srow) * Ks + koff + csrc;
    const u16* Bst = Bt + (size_t)(bn * 256 + srow) * Ks + koff + csrc;

    auto stageA = [&](int h, int kk, int buf) {
        const u16* g = Ast + (size_t)(h * 128) * Ks + kk;
        u16* d = sh + buf * 32768 + h * 8192 + w * 512;
        load_lds16(g, d);
        load_lds16(g + (size_t)64 * Ks, d + 4096);
    };
    auto stageB = [&](int h, int kk, int buf) {
        const u16* g = Bst + (size_t)(h * 128) * Ks + kk;
        u16* d = sh + buf * 32768 + (2 + h) * 8192 + w * 512;
        load_lds16(g, d);
        load_lds16(g + (size_t)64 * Ks, d + 4096);
    };

    f32x4 acc[8][4];
#pragma unroll
    for (int m = 0; m < 8; ++m)
#pragma unroll
        for (int n = 0; n < 4; ++n) acc[m][n] = (f32x4){0.f, 0.f, 0.f, 0.f};

    bf16x8 afl[4][2], afh[4][2], bl[2][2], bh[2][2];
    unsigned shbase = lds_addr(sh);
    unsigned ck0 = (unsigned)((quad ^ sw) * 16);        // ks=0 chunk byte
    unsigned ck1 = ck0 ^ 64u;                           // ks=1 chunk byte
    unsigned Aoff = (unsigned)(wm * 16384 + l16 * 128);             // bytes
    unsigned Boff = (unsigned)((2 + (wn >> 1)) * 16384 + (wn & 1) * 8192
                               + l16 * 128);
    unsigned aB0c = shbase + Aoff + ck0, aB1c = shbase + Aoff + ck1;
    unsigned bB0c = shbase + Boff + ck0, bB1c = shbase + Boff + ck1;

    // prologue: K-tile 0 fully + K-tile 1's B0,A0 (steady-state ring),
    // then issue R1(t=0) = bl+afl from buf0.
    stageB(0, 0, 0); stageA(0, 0, 0); stageA(1, 0, 0); stageB(1, 0, 0);
    stageB(0, 64, 1); stageA(0, 64, 1);
    asm volatile("s_waitcnt vmcnt(4)" ::: "memory");
    BARRIER();
    READ_BL(bB0c, bB1c);
    READ_AFL(aB0c, aB1c);

    for (int t = 0; t < nt; ++t) {
        int buf = t & 1;
        unsigned bo  = (unsigned)buf << 16;             // buf*65536 bytes
        unsigned nbo = (unsigned)(buf ^ 1) << 16;       // next buffer
        unsigned aB0 = aB0c + bo, aB1 = aB1c + bo;
        unsigned bB0 = bB0c + bo, bB1 = bB1c + bo;
        bool s1 = (t + 1 < nt), s2 = (t + 2 < nt);

        // tile top: issue R2 (bh), R3 (afh); stage A1,B1(t+1)
        READ_BH(bB0, bB1);
        READ_AFH(aB0, aB1);
        if (s1) { stageA(1, (t + 1) * 64, buf ^ 1);
                  stageB(1, (t + 1) * 64, buf ^ 1); }

        LGKMN(12);                      // R1 (bl+afl) landed
        __builtin_amdgcn_s_setprio(1);
        MFMA_BLK(afl, bl, 0, 0);        // C1
        __builtin_amdgcn_s_setprio(0);

        LGKMN(8);                       // +R2 (bh) landed
        __builtin_amdgcn_s_setprio(1);
        MFMA_BLK(afl, bh, 0, 2);        // C2; afl dead
        __builtin_amdgcn_s_setprio(0);

        LGKMN(0);                       // all reads of buf done (this wave)
        BARRIER();                      // ... block-wide -> restage safe
        if (s2) { stageB(0, (t + 2) * 64, buf);
                  stageA(0, (t + 2) * 64, buf); }

        __builtin_amdgcn_s_setprio(1);
        MFMA_BLK(afh, bl, 4, 0);        // C3; bl dead
        __builtin_amdgcn_s_setprio(0);

        if (s2)      asm volatile("s_waitcnt vmcnt(4)" ::: "memory");
        else if (s1) asm volatile("s_waitcnt vmcnt(0)" ::: "memory");
        BARRIER();                      // (t+1) in LDS block-wide

        if (s1) {                       // R1'(t+1): drains under C4 + latch
            READ_BL(bB0c + nbo, bB1c + nbo);
            READ_AFL(aB0c + nbo, aB1c + nbo);
        }

        __builtin_amdgcn_s_setprio(1);
        MFMA_BLK(afh, bh, 4, 2);        // C4
        __builtin_amdgcn_s_setprio(0);
    }

    // epilogue
#pragma unroll
    for (int m = 0; m < 8; ++m)
#pragma unroll
        for (int n = 0; n < 4; ++n)
#pragma unroll
            for (int r = 0; r < 4; ++r) {
                int rg = bm * 256 + wm * 128 + m * 16 + quad * 4 + r;
                int cg = bn * 256 + wn * 64 + n * 16 + l16;
                float v = acc[m][n][r];
                if (EPI == 2) {
                    float tv = fmaxf(v, 0.f);
                    ((u16*)out)[(size_t)rg * N + cg] = f2bf(tv * tv);
                } else if (EPI == 4) {          // fused qkv routing
                    if (cg < 2048)      ((float*)out)[(size_t)rg * 2048 + cg] = v;
                    else if (cg < 2560) ((float*)out2)[(size_t)rg * 512 + (cg - 2048)] = v;
                    else                ((u16*)out3)[(size_t)rg * 512 + (cg - 2560)] = f2bf(v);
                } else {                        // EPI 5: split-K bf16 partial
                    u16* p = (blockIdx.z == 0) ? (u16*)out : (u16*)out2;
                    p[(size_t)rg * N + cg] = f2bf(v);
                }
            }
}

// ---------------------------------------------------------------------------
// Flash attention, causal GQA (R11 staged-overlap + R14 defer-max T13).
// ---------------------------------------------------------------------------
__launch_bounds__(256, 2)
__global__ void flash_attn2(const u16* __restrict__ Q, const u16* __restrict__ Kb,
                            const u16* __restrict__ Vt, u16* __restrict__ Y) {
    __shared__ __attribute__((aligned(16))) u16 Qs[128 * 128];
    __shared__ __attribute__((aligned(16))) u16 Ks[64 * 128];
    __shared__ __attribute__((aligned(16))) u16 Vs[2][128 * 64];

    int bid = blockIdx.x;
    int half = bid >> 8, idx = bid & 255;
    int qr = idx & 15;
    int qt = half ? (15 - qr) : qr;
    int bh = (idx >> 4) | (half << 4);
    int b = bh >> 4, h = bh & 15;
    int kvh = h >> 2;
    int q0 = qt * 128;

    int tid = threadIdx.x, lane = tid & 63, wave = tid >> 6;
    int quad = lane >> 4, l16 = lane & 15;

    {   // stage this wave's 32 Q rows (swizzled source chunk)
        int r = lane >> 4;
        for (int c = 0; c < 8; ++c) {
            int row = wave * 32 + c * 4 + r;
            int cc = ((lane & 15) ^ (row & 15)) * 8;
            const u16* g = Q + ((size_t)((b * T_ + q0 + row) * NH_ + h)) * HD_ + cc;
            load_lds16(g, &Qs[(wave * 32 + c * 4) * 128]);
        }
    }
    __syncthreads();

    bf16x8 qf[2][4];
    for (int qtile = 0; qtile < 2; ++qtile)
        for (int kd = 0; kd < 4; ++kd)
            qf[qtile][kd] = *(const bf16x8*)&Qs[(wave * 32 + qtile * 16 + l16) * 128
                                               + (((kd * 4 + quad) ^ l16) * 8)];
    u16* Ps = &Qs[wave * 32 * 128];   // dead Qs slice -> P buffer [32][72]

    auto stageK = [&](int kt) {
        int r = lane >> 4;
        for (int c = 0; c < 4; ++c) {
            int row = wave * 16 + c * 4 + r;
            int cc = ((lane & 15) ^ (row & 15)) * 8;
            const u16* g = Kb + ((size_t)((b * T_ + kt * 64 + row) * NKV_ + kvh)) * HD_ + cc;
            load_lds16(g, &Ks[(wave * 16 + c * 4) * 128]);
        }
    };
    auto stageV = [&](int kt, int vb) {
        int dr = lane >> 3;
        int kc = (((lane & 7) ^ dr)) * 8;
        for (int c = 0; c < 4; ++c) {
            int drow = wave * 32 + c * 8 + dr;
            const u16* g = Vt + ((size_t)((b * NKV_ + kvh) * HD_ + drow)) * T_ + kt * 64 + kc;
            load_lds16(g, &Vs[vb][(wave * 32 + c * 8) * 64]);
        }
    };

    f32x4 zero = {0.f, 0.f, 0.f, 0.f};
    f32x4 o[2][8];
    for (int qtile = 0; qtile < 2; ++qtile)
        for (int dt = 0; dt < 8; ++dt) o[qtile][dt] = zero;
    float m_i[2] = {-__builtin_inff(), -__builtin_inff()};
    float l_i[2] = {0.f, 0.f};
    const float s2s = 0.08838834764831845f * 1.4426950408889634f;  // scale*log2e

    int nkt = 2 * qt + 2;
    stageK(0); stageV(0, 0);          // prologue stage

    for (int kt = 0; kt < nkt; ++kt) {
        int vcur = kt & 1;
        __syncthreads();              // implicit vmcnt(0): K(kt), V(kt) landed

        f32x4 st[2][4];
        for (int qtile = 0; qtile < 2; ++qtile)
            for (int tn = 0; tn < 4; ++tn) st[qtile][tn] = zero;
        __builtin_amdgcn_s_setprio(1);
        for (int tn = 0; tn < 4; ++tn)
            for (int kd = 0; kd < 4; ++kd) {
                bf16x8 kf = *(const bf16x8*)&Ks[(tn * 16 + l16) * 128
                                                + (((kd * 4 + quad) ^ l16) * 8)];
                st[0][tn] = __builtin_amdgcn_mfma_f32_16x16x32_bf16(kf, qf[0][kd], st[0][tn], 0, 0, 0);
                st[1][tn] = __builtin_amdgcn_mfma_f32_16x16x32_bf16(kf, qf[1][kd], st[1][tn], 0, 0, 0);
            }
        __builtin_amdgcn_s_setprio(0);

        __syncthreads();              // all waves done reading Ks (lgkm drained)
        if (kt + 1 < nkt) {           // restage under softmax+PV
            stageK(kt + 1);
            stageV(kt + 1, vcur ^ 1);
        }

        for (int qtile = 0; qtile < 2; ++qtile) {
            int qmin = q0 + wave * 32 + qtile * 16;
            int qg   = qmin + l16;
            bool need_mask = (kt * 64 + 63 > qmin);
            float mx = -__builtin_inff();
            for (int tn = 0; tn < 4; ++tn)
                for (int r = 0; r < 4; ++r) {
                    float v = st[qtile][tn][r] * s2s;
                    if (need_mask) {
                        int key = kt * 64 + tn * 16 + quad * 4 + r;
                        if (key > qg) v = -__builtin_inff();
                    }
                    st[qtile][tn][r] = v;
                    mx = fmaxf(mx, v);
                }
            mx = fmaxf(mx, __shfl_xor(mx, 16, 64));
            mx = fmaxf(mx, __shfl_xor(mx, 32, 64));
            // defer-max (T13, THR=8): keep old max when growth is small;
            // P values then bounded by 2^8 — fine in f32/bf16.
            float al = 1.0f;
            if (!__all(mx - m_i[qtile] <= 8.0f)) {
                float mnew = fmaxf(m_i[qtile], mx);
                al = exp2f(m_i[qtile] - mnew);
                m_i[qtile] = mnew;
            }
            float mref = m_i[qtile];
            float sum = 0.f;
            for (int tn = 0; tn < 4; ++tn) {
                u16x4 pk;
                for (int r = 0; r < 4; ++r) {
                    float e = exp2f(st[qtile][tn][r] - mref);
                    sum += e;
                    pk[r] = f2bf(e);
                }
                *(u16x4*)&Ps[(qtile * 16 + l16) * 72 + tn * 16 + quad * 4] = pk;
            }
            sum += __shfl_xor(sum, 16, 64);
            sum += __shfl_xor(sum, 32, 64);
            l_i[qtile] = l_i[qtile] * al + sum;
            if (al != 1.0f) {             // wave-uniform (set in uniform branch)
                float aB[4];
                for (int r = 0; r < 4; ++r) aB[r] = __shfl(al, quad * 4 + r, 64);
                for (int dt = 0; dt < 8; ++dt)
                    for (int r = 0; r < 4; ++r) o[qtile][dt][r] *= aB[r];
            }
        }

        bf16x8 pf[2][2];
        for (int qtile = 0; qtile < 2; ++qtile)
            for (int ks = 0; ks < 2; ++ks)
                pf[qtile][ks] = *(const bf16x8*)&Ps[(qtile * 16 + l16) * 72 + ks * 32 + quad * 8];
        __builtin_amdgcn_s_setprio(1);
        for (int ks = 0; ks < 2; ++ks)
            for (int dt = 0; dt < 8; ++dt) {
                bf16x8 vf = *(const bf16x8*)&Vs[vcur][(dt * 16 + l16) * 64
                                                + (((ks * 4 + quad) ^ (l16 & 7)) * 8)];
                o[0][dt] = __builtin_amdgcn_mfma_f32_16x16x32_bf16(pf[0][ks], vf, o[0][dt], 0, 0, 0);
                o[1][dt] = __builtin_amdgcn_mfma_f32_16x16x32_bf16(pf[1][ks], vf, o[1][dt], 0, 0, 0);
            }
        __builtin_amdgcn_s_setprio(0);
    }

    for (int qtile = 0; qtile < 2; ++qtile) {
        float inv = 1.0f / l_i[qtile];
        float iB[4];
        for (int r = 0; r < 4; ++r) iB[r] = __shfl(inv, quad * 4 + r, 64);
        for (int r = 0; r < 4; ++r) {
            int qg = q0 + wave * 32 + qtile * 16 + quad * 4 + r;
            u16* yr = Y + ((size_t)((b * T_ + qg) * NH_ + h)) * HD_;
            for (int dt = 0; dt < 8; ++dt)
                yr[dt * 16 + l16] = f2bf(o[qtile][dt][r] * iB[r]);
        }
    }
}

// ---------------------------------------------------------------------------
extern "C" void kernel_launch(void* const* d_in, const int* in_sizes, int n_in,
                              void* d_out, int out_size, void* d_ws, size_t ws_size,
                              hipStream_t stream) {
    const float* x     = (const float*)d_in[0];
    const float* cosb  = (const float*)d_in[1];
    const float* sinb  = (const float*)d_in[2];
    const float* wq    = (const float*)d_in[3];
    const float* wk    = (const float*)d_in[4];
    const float* wv    = (const float*)d_in[5];
    const float* wo    = (const float*)d_in[6];
    const float* wfc   = (const float*)d_in[7];
    const float* wproj = (const float*)d_in[8];

    char* ws = (char*)d_ws;
    size_t off = 0;
    auto alloc = [&](size_t bytes) { char* p = ws + off; off += (bytes + 255) & ~(size_t)255; return p; };

    u16*   wqkvT  = (u16*)alloc((size_t)3072 * C_ * 2);        // rows: q | k | v
    u16*   woT    = (u16*)alloc((size_t)C_ * C_ * 2);
    u16*   wfcT   = (u16*)alloc((size_t)DFF_ * C_ * 2);        // [8192][2048]
    u16*   wprojT = (u16*)alloc((size_t)C_ * DFF_ * 2);        // [2048][8192]
    u16*   hbuf   = (u16*)alloc((size_t)B_ * T_ * C_ * 2);     // h / p0 buffers
    float* x2     = (float*)alloc((size_t)B_ * T_ * C_ * 4);   // post-attn residual
    u16*   ybuf   = (u16*)alloc((size_t)B_ * T_ * C_ * 2);     // attn out / proj p1
    u16*   Vtb    = (u16*)alloc((size_t)B_ * NKV_ * HD_ * T_ * 2);  // V transposed
    // 64MB scratch: qkv temporaries -> wo partial p1 -> ffbuf
    char*  scratch = alloc((size_t)B_ * T_ * DFF_ * 2);
    float* q_tmp  = (float*)scratch;                                     // 32MB
    float* k_tmp  = (float*)(scratch + (size_t)B_ * T_ * C_ * 4);        // 8MB
    u16*   qb     = (u16*)(scratch + (size_t)B_ * T_ * C_ * 4 + (size_t)B_ * T_ * 512 * 4);
    u16*   kb     = (u16*)((char*)qb + (size_t)B_ * T_ * C_ * 2);
    u16*   vb     = (u16*)((char*)kb + (size_t)B_ * T_ * 512 * 2);
    u16*   wop1   = (u16*)scratch;       // wo split-K partial 1 (q_tmp dead by then)
    u16*   ffbuf  = (u16*)scratch;       // [4096][8192] bf16 (after reduce_rms)

    const int M = B_ * T_;   // 4096
    dim3 tb(256);

    // 1+2. weights -> bf16 [N][K] AND h = rmsnorm(x), ONE launch.
    TD6 td;
    td.t[0] = { wq,    wqkvT,                       C_,   C_,   0 };     // 1024
    td.t[1] = { wk,    wqkvT + (size_t)2048 * C_,   C_,   512,  1024 };  // 256
    td.t[2] = { wv,    wqkvT + (size_t)2560 * C_,   C_,   512,  1280 };  // 256
    td.t[3] = { wo,    woT,                         C_,   C_,   1536 };  // 1024
    td.t[4] = { wfc,   wfcT,                        C_,   DFF_, 2560 };  // 4096
    td.t[5] = { wproj, wprojT,                      DFF_, C_,   6656 };  // 4096
    prep_all<<<dim3(TRBLKS_ + M), tb, 0, stream>>>(td, x, hbuf);

    // 3. fused q/k/v projection (N=3072): 12x16 = 192 blocks
    gemm256<4><<<dim3(3072 / 256, M / 256), dim3(512), 0, stream>>>(
        hbuf, wqkvT, q_tmp, k_tmp, vb, M, 3072, C_, C_);

    // 4. RoPE + qk-rmsnorm AND V transpose, ONE launch
    rope_tv<<<dim3(TVB_ + (B_ * T_ * (NH_ + NKV_)) / 4), tb, 0, stream>>>(
        q_tmp, k_tmp, cosb, sinb, qb, kb, vb, Vtb);

    // 5. causal GQA flash attention (512 blocks, 2/CU)
    flash_attn2<<<dim3(512), tb, 0, stream>>>(qb, kb, Vtb, ybuf);

    // 6. wo split-K=2: partials -> hbuf (z=0), wop1 (z=1); 8x16x2 = 256 blocks
    gemm256<5><<<dim3(C_ / 256, M / 256, 2), dim3(512), 0, stream>>>(
        ybuf, woT, hbuf, wop1, nullptr, M, C_, C_ / 2, C_);

    // 7. x2 = x + p0 + p1;  hbuf = rmsnorm(x2)   (p0 aliases hbuf — safe)
    reduce_rms<<<M, tb, 0, stream>>>(x, hbuf, wop1, x2, hbuf);

    // 8. ff = relu(h2 @ w_fc)^2   (ffbuf overwrites scratch after step 7)
    gemm256<2><<<dim3(DFF_ / 256, M / 256), dim3(512), 0, stream>>>(
        hbuf, wfcT, ffbuf, nullptr, nullptr, M, DFF_, C_, C_);

    // 9. proj split-K=2: partials -> hbuf (z=0), ybuf (z=1); 256 blocks
    gemm256<5><<<dim3(C_ / 256, M / 256, 2), dim3(512), 0, stream>>>(
        ffbuf, wprojT, hbuf, ybuf, nullptr, M, C_, DFF_ / 2, DFF_);

    // 10. out = x2 + p0 + p1
    reduce_out<<<dim3((M * C_) / 1024), tb, 0, stream>>>(x2, hbuf, ybuf, (float*)d_out);
}

// Round 11
// 671.006 us; speedup vs baseline: 1.1998x; 1.1998x over previous
//
#include <hip/hip_runtime.h>
#include <cstdint>
#include <cstddef>

// ---------------------------------------------------------------------------
// Transformer block, B=2 T=2048 C=2048 NH=16 NKV=4 HD=128 DFF=8192, gfx950.
// R15: REVERT gemm256 to the best-measured form (R9 counted-lgkm K-loop +
// R13 square-supertile XCD mapping; fc=127.9us, MfmaUtil 46.6%, FETCH 98MB).
// R14's cross-tile R1 read-ahead regressed (167us, MfmaUtil 34%) — second
// failure of in-place LDS read-ahead (WAR scoreboard serialization against
// in-flight MFMAs + thin cover); that lever is closed. Kept: R11 attn
// staged-overlap + R14 defer-max (T13; innocent in the R14 regression),
// R12 prep_all, R13 rope_tv.
// ---------------------------------------------------------------------------

#define B_    2
#define T_    2048
#define C_    2048
#define NH_   16
#define NKV_  4
#define HD_   128
#define DFF_  8192
#define EPS_  1.1920928955078125e-07f   // jnp.finfo(float32).eps

typedef short          bf16x8 __attribute__((ext_vector_type(8)));
typedef float          f32x4  __attribute__((ext_vector_type(4)));
typedef unsigned short u16;
typedef unsigned short u16x8  __attribute__((ext_vector_type(8)));
typedef unsigned short u16x4  __attribute__((ext_vector_type(4)));

__device__ __forceinline__ u16 f2bf(float f) {
    unsigned u = __float_as_uint(f);
    unsigned r = u + 0x7fffu + ((u >> 16) & 1u);   // RNE; inputs are finite
    return (u16)(r >> 16);
}
__device__ __forceinline__ float bf2f(u16 u) {
    return __uint_as_float((unsigned)u << 16);
}

__device__ __forceinline__ void load_lds16(const void* g, void* l) {
    // 16B per lane, LDS dest = wave-uniform base + lane*16 (guide §5 caveat)
    __builtin_amdgcn_global_load_lds(
        (__attribute__((address_space(1))) void*)(g),
        (__attribute__((address_space(3))) void*)(l), 16, 0, 0);
}

// LDS byte address of a pointer into __shared__
__device__ __forceinline__ unsigned lds_addr(const void* p) {
    return (unsigned)(unsigned long long)(__attribute__((address_space(3))) const void*)p;
}

// ---------------------------------------------------------------------------
// prep_all: (a) 6 weight transposes f32[K][N] -> bf16[N][K] in 32x128 tiles,
// (b) rmsnorm rows of x (blocks >= TRBLKS). One launch, 256 threads.
// ---------------------------------------------------------------------------
struct TD  { const float* src; u16* dst; int K, N, boff; };
struct TD6 { TD t[6]; };

#define TRBLKS_ 10752

__global__ void prep_all(TD6 d, const float* __restrict__ x, u16* __restrict__ hout) {
    __shared__ u16 tile[32][136];          // 8.7 KB; rows 272B (17x16B)
    __shared__ float part[4];
    int bid = blockIdx.x;
    int tid = threadIdx.x;

    if (bid >= TRBLKS_) {                  // ---- rmsnorm branch ----
        int row = bid - TRBLKS_;
        const float4* xr = (const float4*)(x + (size_t)row * C_);
        float4 a = xr[tid];
        float4 b = xr[tid + 256];
        float ss = a.x * a.x + a.y * a.y + a.z * a.z + a.w * a.w
                 + b.x * b.x + b.y * b.y + b.z * b.z + b.w * b.w;
        for (int m = 1; m < 64; m <<= 1) ss += __shfl_xor(ss, m, 64);
        if ((tid & 63) == 0) part[tid >> 6] = ss;
        __syncthreads();
        float tot = part[0] + part[1] + part[2] + part[3];
        float sc = rsqrtf(tot * (1.0f / C_) + EPS_);
        u16x4 o1, o2;
        o1[0] = f2bf(a.x * sc); o1[1] = f2bf(a.y * sc); o1[2] = f2bf(a.z * sc); o1[3] = f2bf(a.w * sc);
        o2[0] = f2bf(b.x * sc); o2[1] = f2bf(b.y * sc); o2[2] = f2bf(b.z * sc); o2[3] = f2bf(b.w * sc);
        u16x4* orow = (u16x4*)(hout + (size_t)row * C_);
        orow[tid]       = o1;
        orow[tid + 256] = o2;
        return;
    }

    // ---- transpose branch ----
    int di = 0;
    for (int i = 5; i > 0; --i) if (bid >= d.t[i].boff) { di = i; break; }
    const float* src = d.t[di].src;
    u16* dst = d.t[di].dst;
    int K = d.t[di].K, N = d.t[di].N;
    int lb = bid - d.t[di].boff;
    int nx = N >> 5;                       // N/32 tiles along n
    int n0 = (lb % nx) * 32;
    int k0 = (lb / nx) * 128;

    int kr = tid >> 3;                     // 0..31
    int nc = (tid & 7) * 4;                // 0,4,...,28
    for (int r = 0; r < 4; ++r) {
        int kk = kr + r * 32;              // 0..127
        float4 v = *(const float4*)&src[(size_t)(k0 + kk) * N + n0 + nc];
        tile[nc + 0][kk] = f2bf(v.x);
        tile[nc + 1][kk] = f2bf(v.y);
        tile[nc + 2][kk] = f2bf(v.z);
        tile[nc + 3][kk] = f2bf(v.w);
    }
    __syncthreads();
    int nL = tid >> 4;                     // 0..15
    int kc = (tid & 15) * 8;               // 0..120
    for (int w2 = 0; w2 < 2; ++w2) {
        int n = nL + w2 * 16;
        u16x8 o = *(const u16x8*)&tile[n][kc];
        *(u16x8*)&dst[(size_t)(n0 + n) * K + k0 + kc] = o;
    }
}

// ---------------------------------------------------------------------------
// rope_tv: merged RoPE+qk-rmsnorm AND V transpose in one launch.
// ---------------------------------------------------------------------------
#define TVB_ 1024

__global__ void rope_tv(const float* __restrict__ Xq, const float* __restrict__ Xk,
                        const float* __restrict__ cosb, const float* __restrict__ sinb,
                        u16* __restrict__ Oq, u16* __restrict__ Ok,
                        const u16* __restrict__ vb, u16* __restrict__ Vt) {
    int bid = blockIdx.x;
    if (bid < TVB_) {                      // ---- V transpose branch ----
        int bxx  = bid & 127;
        int kvh  = (bid >> 7) & 3;
        int b    = bid >> 9;
        int dblk = bxx & 1;
        int t0   = (bxx >> 1) * 32;
        int dl   = threadIdx.x & 63;
        int tc   = threadIdx.x >> 6;       // 0..3
        int d    = dblk * 64 + dl;
        u16x8 v8;
        for (int j = 0; j < 8; ++j) {
            int t = t0 + tc * 8 + j;
            v8[j] = vb[((size_t)(b * T_ + t) * NKV_ + kvh) * HD_ + d];
        }
        *(u16x8*)(Vt + ((size_t)((b * NKV_ + kvh) * HD_ + d)) * T_ + t0 + tc * 8) = v8;
        return;
    }
    int gw   = (int)(((bid - TVB_) * blockDim.x + threadIdx.x) >> 6);
    int lane = threadIdx.x & 63;
    const float* X; u16* O; int t;
    if (gw < B_ * T_ * NH_) {
        X = Xq + (size_t)gw * HD_;  O = Oq + (size_t)gw * HD_;  t = (gw / NH_) % T_;
    } else {
        int w2 = gw - B_ * T_ * NH_;
        X = Xk + (size_t)w2 * HD_;  O = Ok + (size_t)w2 * HD_;  t = (w2 / NKV_) % T_;
    }
    float x1 = X[lane];
    float x2 = X[64 + lane];
    float c  = cosb[t * 64 + lane];
    float sn = sinb[t * 64 + lane];
    float r1 = x1 * c + x2 * sn;
    float r2 = x2 * c - x1 * sn;
    float ss = r1 * r1 + r2 * r2;
    for (int m = 1; m < 64; m <<= 1) ss += __shfl_xor(ss, m, 64);
    float sc = rsqrtf(ss * (1.0f / HD_) + EPS_);
    O[lane]      = f2bf(r1 * sc);
    O[64 + lane] = f2bf(r2 * sc);
}

// ---------------------------------------------------------------------------
// Fused split-K reduce + residual + RMSNorm:
//   x2 = x + p0 + p1 (bf16 partials);  hout = rmsnorm(x2) bf16
// NOTE: p0 may alias hout (read-before-write, same indices).
// ---------------------------------------------------------------------------
__global__ void reduce_rms(const float* __restrict__ x, const u16* __restrict__ p0,
                           const u16* __restrict__ p1, float* __restrict__ x2,
                           u16* __restrict__ hout) {
    int row = blockIdx.x;
    const float4* xr = (const float4*)(x + (size_t)row * C_);
    const u16x4* a0 = (const u16x4*)(p0 + (size_t)row * C_);
    const u16x4* a1 = (const u16x4*)(p1 + (size_t)row * C_);
    float4 v[2];
    float ss = 0.f;
    for (int h = 0; h < 2; ++h) {
        int idx = threadIdx.x + h * 256;
        float4 xv = xr[idx];
        u16x4 b0 = a0[idx], b1 = a1[idx];
        v[h].x = xv.x + bf2f(b0[0]) + bf2f(b1[0]);
        v[h].y = xv.y + bf2f(b0[1]) + bf2f(b1[1]);
        v[h].z = xv.z + bf2f(b0[2]) + bf2f(b1[2]);
        v[h].w = xv.w + bf2f(b0[3]) + bf2f(b1[3]);
        ss += v[h].x * v[h].x + v[h].y * v[h].y + v[h].z * v[h].z + v[h].w * v[h].w;
    }
    for (int m = 1; m < 64; m <<= 1) ss += __shfl_xor(ss, m, 64);
    __shared__ float part[4];
    if ((threadIdx.x & 63) == 0) part[threadIdx.x >> 6] = ss;
    __syncthreads();
    float tot = part[0] + part[1] + part[2] + part[3];
    float sc = rsqrtf(tot * (1.0f / C_) + EPS_);
    float4* x2r = (float4*)(x2 + (size_t)row * C_);
    u16x4* hr   = (u16x4*)(hout + (size_t)row * C_);
    for (int h = 0; h < 2; ++h) {
        int idx = threadIdx.x + h * 256;
        x2r[idx] = v[h];
        u16x4 o;
        o[0] = f2bf(v[h].x * sc); o[1] = f2bf(v[h].y * sc);
        o[2] = f2bf(v[h].z * sc); o[3] = f2bf(v[h].w * sc);
        hr[idx] = o;
    }
}

// ---------------------------------------------------------------------------
// Final split-K reduce + residual: out = x2 + p0 + p1  (elementwise, f32)
// ---------------------------------------------------------------------------
__global__ void reduce_out(const float* __restrict__ x2, const u16* __restrict__ p0,
                           const u16* __restrict__ p1, float* __restrict__ out) {
    size_t i = (size_t)blockIdx.x * 256 + threadIdx.x;
    float4 xv = ((const float4*)x2)[i];
    u16x4 b0 = ((const u16x4*)p0)[i];
    u16x4 b1 = ((const u16x4*)p1)[i];
    float4 o;
    o.x = xv.x + bf2f(b0[0]) + bf2f(b1[0]);
    o.y = xv.y + bf2f(b0[1]) + bf2f(b1[1]);
    o.z = xv.z + bf2f(b0[2]) + bf2f(b1[2]);
    o.w = xv.w + bf2f(b0[3]) + bf2f(b1[3]);
    ((float4*)out)[i] = o;
}

// ---------------------------------------------------------------------------
// 256x256 GEMM, counted-lgkm pipelined K-loop (R9 schedule, best measured)
// + R13 square per-XCD supertile mapping (FETCH 270->98 MB verified).
// Per K-tile t (buf = t&1), 2 barriers total:
//   top:  24x ds_read_b128 (afl 8, bl 4, bh 4, afh 8, in this order)
//         stage A1,B1(t+1) -> buf^1
//   lgkmcnt(12): afl+bl done   -> MFMA(afl,bl)
//   lgkmcnt(8) : +bh done      -> MFMA(afl,bh)
//   lgkmcnt(0) + BARRIER       -> stage B0,A0(t+2) -> buf
//   MFMA(afh,bl); MFMA(afh,bh)
//   vmcnt(4) + BARRIER
// EPI: 2=relu^2->bf16, 4=qkv routing, 5=split-K bf16 partial.
// ---------------------------------------------------------------------------

#define BARRIER() do { __builtin_amdgcn_s_barrier();                     \
                       asm volatile("" ::: "memory"); } while (0)
#define LGKMN(N)  do { asm volatile("s_waitcnt lgkmcnt(" #N ")" ::: "memory");\
                       __builtin_amdgcn_sched_barrier(0); } while (0)

#define DSR(dst, base, lit)                                              \
    asm volatile("ds_read_b128 %0, %1 offset:" lit : "=v"(dst) : "v"(base))

#define READ_AFL() do {                                                  \
    DSR(afl[0][0], aB0, "0");     DSR(afl[0][1], aB1, "0");              \
    DSR(afl[1][0], aB0, "2048");  DSR(afl[1][1], aB1, "2048");           \
    DSR(afl[2][0], aB0, "4096");  DSR(afl[2][1], aB1, "4096");           \
    DSR(afl[3][0], aB0, "6144");  DSR(afl[3][1], aB1, "6144"); } while (0)

#define READ_AFH() do {                                                  \
    DSR(afh[0][0], aB0, "8192");  DSR(afh[0][1], aB1, "8192");           \
    DSR(afh[1][0], aB0, "10240"); DSR(afh[1][1], aB1, "10240");          \
    DSR(afh[2][0], aB0, "12288"); DSR(afh[2][1], aB1, "12288");          \
    DSR(afh[3][0], aB0, "14336"); DSR(afh[3][1], aB1, "14336"); } while (0)

#define READ_BL() do {                                                   \
    DSR(bl[0][0], bB0, "0");     DSR(bl[0][1], bB1, "0");                \
    DSR(bl[1][0], bB0, "2048");  DSR(bl[1][1], bB1, "2048"); } while (0)

#define READ_BH() do {                                                   \
    DSR(bh[0][0], bB0, "4096");  DSR(bh[0][1], bB1, "4096");             \
    DSR(bh[1][0], bB0, "6144");  DSR(bh[1][1], bB1, "6144"); } while (0)

#define MFMA_BLK(AF, BF, MB, NB)                                             \
    _Pragma("unroll")                                                        \
    for (int ks = 0; ks < 2; ++ks)                                           \
        _Pragma("unroll")                                                    \
        for (int mi = 0; mi < 4; ++mi)                                       \
            _Pragma("unroll")                                                \
            for (int ni = 0; ni < 2; ++ni)                                   \
                acc[MB + mi][NB + ni] =                                      \
                    __builtin_amdgcn_mfma_f32_16x16x32_bf16(                 \
                        AF[mi][ks], BF[ni][ks], acc[MB + mi][NB + ni], 0, 0, 0);

template <int EPI>
__launch_bounds__(512, 1)
__global__ void gemm256(const u16* __restrict__ A, const u16* __restrict__ Bt,
                        void* __restrict__ out, void* __restrict__ out2,
                        void* __restrict__ out3, int M, int N, int K, int Ks) {
    // 128 KiB static LDS (gfx950 limit 160 KiB/WG)
    __shared__ __attribute__((aligned(16))) u16 sh[65536];

    int tid  = threadIdx.x;
    int l    = tid & 63;
    int w    = tid >> 6;          // 0..7
    int l16  = l & 15;
    int quad = l >> 4;            // 0..3
    int sw   = l & 7;             // read-side swizzle key
    int wm   = w >> 2, wn = w & 3;

    // T1 + R13: XCD-contiguous chunks, square supertile order inside.
    int nwg = gridDim.x * gridDim.y;
    int id  = blockIdx.y * gridDim.x + blockIdx.x;
    int cpx = nwg >> 3;
    int sid = (id & 7) * cpx + (id >> 3);
    int GN   = (cpx >= 64) ? 8 : 4;
    int span = gridDim.y * GN;
    int bnb  = sid / span;
    int r0   = sid % span;
    int bm   = r0 / GN;
    int bn   = bnb * GN + (r0 % GN);

    size_t koff = (size_t)blockIdx.z * K;
    int nt = K >> 6;              // all our launches: nt >= 16

    // staging: lane covers LDS row (w*8 + l/8), chunk l%8; source chunk is
    // pre-swizzled so swizzled reads see the right data (rule #21)
    int csrc = ((l & 7) ^ ((l >> 3) & 7)) * 8;
    int srow = w * 8 + (l >> 3);
    const u16* Ast = A  + (size_t)(bm * 256 + srow) * Ks + koff + csrc;
    const u16* Bst = Bt + (size_t)(bn * 256 + srow) * Ks + koff + csrc;

    auto stageA = [&](int h, int kk, int buf) {
        const u16* g = Ast + (size_t)(h * 128) * Ks + kk;
        u16* d = sh + buf * 32768 + h * 8192 + w * 512;
        load_lds16(g, d);
        load_lds16(g + (size_t)64 * Ks, d + 4096);
    };
    auto stageB = [&](int h, int kk, int buf) {
        const u16* g = Bst + (size_t)(h * 128) * Ks + kk;
        u16* d = sh + buf * 32768 + (2 + h) * 8192 + w * 512;
        load_lds16(g, d);
        load_lds16(g + (size_t)64 * Ks, d + 4096);
    };

    f32x4 acc[8][4];
#pragma unroll
    for (int m = 0; m < 8; ++m)
#pragma unroll
        for (int n = 0; n < 4; ++n) acc[m][n] = (f32x4){0.f, 0.f, 0.f, 0.f};

    // prologue: K-tile 0 fully + K-tile 1's B0,A0 (matches steady-state ring)
    stageB(0, 0, 0); stageA(0, 0, 0); stageA(1, 0, 0); stageB(1, 0, 0);
    stageB(0, 64, 1); stageA(0, 64, 1);
    asm volatile("s_waitcnt vmcnt(4)" ::: "memory");
    BARRIER();

    bf16x8 afl[4][2], afh[4][2], bl[2][2], bh[2][2];
    unsigned shbase = lds_addr(sh);
    unsigned ck0 = (unsigned)((quad ^ sw) * 16);        // ks=0 chunk byte
    unsigned ck1 = ck0 ^ 64u;                           // ks=1 chunk byte
    unsigned Aoff = (unsigned)(wm * 16384 + l16 * 128);             // bytes
    unsigned Boff = (unsigned)((2 + (wn >> 1)) * 16384 + (wn & 1) * 8192
                               + l16 * 128);
    unsigned aB0c = shbase + Aoff + ck0, aB1c = shbase + Aoff + ck1;
    unsigned bB0c = shbase + Boff + ck0, bB1c = shbase + Boff + ck1;

    for (int t = 0; t < nt; ++t) {
        int buf = t & 1;
        unsigned bo  = (unsigned)buf << 16;             // buf*65536 bytes
        unsigned aB0 = aB0c + bo, aB1 = aB1c + bo;
        unsigned bB0 = bB0c + bo, bB1 = bB1c + bo;
        bool s1 = (t + 1 < nt), s2 = (t + 2 < nt);

        // tile top: all 24 reads (order: afl, bl, bh, afh), then prefetch
        READ_AFL();
        READ_BL();
        READ_BH();
        READ_AFH();
        if (s1) { stageA(1, (t + 1) * 64, buf ^ 1);
                  stageB(1, (t + 1) * 64, buf ^ 1); }

        LGKMN(12);                      // afl+bl landed; bh+afh draining
        __builtin_amdgcn_s_setprio(1);
        MFMA_BLK(afl, bl, 0, 0);
        __builtin_amdgcn_s_setprio(0);

        LGKMN(8);                       // +bh landed
        __builtin_amdgcn_s_setprio(1);
        MFMA_BLK(afl, bh, 0, 2);
        __builtin_amdgcn_s_setprio(0);

        LGKMN(0);                       // all reads of buf done (this wave)
        BARRIER();                      // ... and block-wide -> restage safe
        if (s2) { stageB(0, (t + 2) * 64, buf);
                  stageA(0, (t + 2) * 64, buf); }

        __builtin_amdgcn_s_setprio(1);
        MFMA_BLK(afh, bl, 4, 0);
        MFMA_BLK(afh, bh, 4, 2);
        __builtin_amdgcn_s_setprio(0);

        if (s2)      asm volatile("s_waitcnt vmcnt(4)" ::: "memory");
        else if (s1) asm volatile("s_waitcnt vmcnt(0)" ::: "memory");
        BARRIER();
    }

    // epilogue
#pragma unroll
    for (int m = 0; m < 8; ++m)
#pragma unroll
        for (int n = 0; n < 4; ++n)
#pragma unroll
            for (int r = 0; r < 4; ++r) {
                int rg = bm * 256 + wm * 128 + m * 16 + quad * 4 + r;
                int cg = bn * 256 + wn * 64 + n * 16 + l16;
                float v = acc[m][n][r];
                if (EPI == 2) {
                    float tv = fmaxf(v, 0.f);
                    ((u16*)out)[(size_t)rg * N + cg] = f2bf(tv * tv);
                } else if (EPI == 4) {          // fused qkv routing
                    if (cg < 2048)      ((float*)out)[(size_t)rg * 2048 + cg] = v;
                    else if (cg < 2560) ((float*)out2)[(size_t)rg * 512 + (cg - 2048)] = v;
                    else                ((u16*)out3)[(size_t)rg * 512 + (cg - 2560)] = f2bf(v);
                } else {                        // EPI 5: split-K bf16 partial
                    u16* p = (blockIdx.z == 0) ? (u16*)out : (u16*)out2;
                    p[(size_t)rg * N + cg] = f2bf(v);
                }
            }
}

// ---------------------------------------------------------------------------
// Flash attention, causal GQA (R11 staged-overlap + defer-max T13).
// ---------------------------------------------------------------------------
__launch_bounds__(256, 2)
__global__ void flash_attn2(const u16* __restrict__ Q, const u16* __restrict__ Kb,
                            const u16* __restrict__ Vt, u16* __restrict__ Y) {
    __shared__ __attribute__((aligned(16))) u16 Qs[128 * 128];
    __shared__ __attribute__((aligned(16))) u16 Ks[64 * 128];
    __shared__ __attribute__((aligned(16))) u16 Vs[2][128 * 64];

    int bid = blockIdx.x;
    int half = bid >> 8, idx = bid & 255;
    int qr = idx & 15;
    int qt = half ? (15 - qr) : qr;
    int bh = (idx >> 4) | (half << 4);
    int b = bh >> 4, h = bh & 15;
    int kvh = h >> 2;
    int q0 = qt * 128;

    int tid = threadIdx.x, lane = tid & 63, wave = tid >> 6;
    int quad = lane >> 4, l16 = lane & 15;

    {   // stage this wave's 32 Q rows (swizzled source chunk)
        int r = lane >> 4;
        for (int c = 0; c < 8; ++c) {
            int row = wave * 32 + c * 4 + r;
            int cc = ((lane & 15) ^ (row & 15)) * 8;
            const u16* g = Q + ((size_t)((b * T_ + q0 + row) * NH_ + h)) * HD_ + cc;
            load_lds16(g, &Qs[(wave * 32 + c * 4) * 128]);
        }
    }
    __syncthreads();

    bf16x8 qf[2][4];
    for (int qtile = 0; qtile < 2; ++qtile)
        for (int kd = 0; kd < 4; ++kd)
            qf[qtile][kd] = *(const bf16x8*)&Qs[(wave * 32 + qtile * 16 + l16) * 128
                                               + (((kd * 4 + quad) ^ l16) * 8)];
    u16* Ps = &Qs[wave * 32 * 128];   // dead Qs slice -> P buffer [32][72]

    auto stageK = [&](int kt) {
        int r = lane >> 4;
        for (int c = 0; c < 4; ++c) {
            int row = wave * 16 + c * 4 + r;
            int cc = ((lane & 15) ^ (row & 15)) * 8;
            const u16* g = Kb + ((size_t)((b * T_ + kt * 64 + row) * NKV_ + kvh)) * HD_ + cc;
            load_lds16(g, &Ks[(wave * 16 + c * 4) * 128]);
        }
    };
    auto stageV = [&](int kt, int vb) {
        int dr = lane >> 3;
        int kc = (((lane & 7) ^ dr)) * 8;
        for (int c = 0; c < 4; ++c) {
            int drow = wave * 32 + c * 8 + dr;
            const u16* g = Vt + ((size_t)((b * NKV_ + kvh) * HD_ + drow)) * T_ + kt * 64 + kc;
            load_lds16(g, &Vs[vb][(wave * 32 + c * 8) * 64]);
        }
    };

    f32x4 zero = {0.f, 0.f, 0.f, 0.f};
    f32x4 o[2][8];
    for (int qtile = 0; qtile < 2; ++qtile)
        for (int dt = 0; dt < 8; ++dt) o[qtile][dt] = zero;
    float m_i[2] = {-__builtin_inff(), -__builtin_inff()};
    float l_i[2] = {0.f, 0.f};
    const float s2s = 0.08838834764831845f * 1.4426950408889634f;  // scale*log2e

    int nkt = 2 * qt + 2;
    stageK(0); stageV(0, 0);          // prologue stage

    for (int kt = 0; kt < nkt; ++kt) {
        int vcur = kt & 1;
        __syncthreads();              // implicit vmcnt(0): K(kt), V(kt) landed

        f32x4 st[2][4];
        for (int qtile = 0; qtile < 2; ++qtile)
            for (int tn = 0; tn < 4; ++tn) st[qtile][tn] = zero;
        __builtin_amdgcn_s_setprio(1);
        for (int tn = 0; tn < 4; ++tn)
            for (int kd = 0; kd < 4; ++kd) {
                bf16x8 kf = *(const bf16x8*)&Ks[(tn * 16 + l16) * 128
                                                + (((kd * 4 + quad) ^ l16) * 8)];
                st[0][tn] = __builtin_amdgcn_mfma_f32_16x16x32_bf16(kf, qf[0][kd], st[0][tn], 0, 0, 0);
                st[1][tn] = __builtin_amdgcn_mfma_f32_16x16x32_bf16(kf, qf[1][kd], st[1][tn], 0, 0, 0);
            }
        __builtin_amdgcn_s_setprio(0);

        __syncthreads();              // all waves done reading Ks (lgkm drained)
        if (kt + 1 < nkt) {           // restage under softmax+PV
            stageK(kt + 1);
            stageV(kt + 1, vcur ^ 1);
        }

        for (int qtile = 0; qtile < 2; ++qtile) {
            int qmin = q0 + wave * 32 + qtile * 16;
            int qg   = qmin + l16;
            bool need_mask = (kt * 64 + 63 > qmin);
            float mx = -__builtin_inff();
            for (int tn = 0; tn < 4; ++tn)
                for (int r = 0; r < 4; ++r) {
                    float v = st[qtile][tn][r] * s2s;
                    if (need_mask) {
                        int key = kt * 64 + tn * 16 + quad * 4 + r;
                        if (key > qg) v = -__builtin_inff();
                    }
                    st[qtile][tn][r] = v;
                    mx = fmaxf(mx, v);
                }
            mx = fmaxf(mx, __shfl_xor(mx, 16, 64));
            mx = fmaxf(mx, __shfl_xor(mx, 32, 64));
            // defer-max (T13, THR=8): keep old max when growth is small;
            // P values then bounded by 2^8 — fine in f32/bf16.
            float al = 1.0f;
            if (!__all(mx - m_i[qtile] <= 8.0f)) {
                float mnew = fmaxf(m_i[qtile], mx);
                al = exp2f(m_i[qtile] - mnew);
                m_i[qtile] = mnew;
            }
            float mref = m_i[qtile];
            float sum = 0.f;
            for (int tn = 0; tn < 4; ++tn) {
                u16x4 pk;
                for (int r = 0; r < 4; ++r) {
                    float e = exp2f(st[qtile][tn][r] - mref);
                    sum += e;
                    pk[r] = f2bf(e);
                }
                *(u16x4*)&Ps[(qtile * 16 + l16) * 72 + tn * 16 + quad * 4] = pk;
            }
            sum += __shfl_xor(sum, 16, 64);
            sum += __shfl_xor(sum, 32, 64);
            l_i[qtile] = l_i[qtile] * al + sum;
            if (al != 1.0f) {             // wave-uniform (set in uniform branch)
                float aB[4];
                for (int r = 0; r < 4; ++r) aB[r] = __shfl(al, quad * 4 + r, 64);
                for (int dt = 0; dt < 8; ++dt)
                    for (int r = 0; r < 4; ++r) o[qtile][dt][r] *= aB[r];
            }
        }

        bf16x8 pf[2][2];
        for (int qtile = 0; qtile < 2; ++qtile)
            for (int ks = 0; ks < 2; ++ks)
                pf[qtile][ks] = *(const bf16x8*)&Ps[(qtile * 16 + l16) * 72 + ks * 32 + quad * 8];
        __builtin_amdgcn_s_setprio(1);
        for (int ks = 0; ks < 2; ++ks)
            for (int dt = 0; dt < 8; ++dt) {
                bf16x8 vf = *(const bf16x8*)&Vs[vcur][(dt * 16 + l16) * 64
                                                + (((ks * 4 + quad) ^ (l16 & 7)) * 8)];
                o[0][dt] = __builtin_amdgcn_mfma_f32_16x16x32_bf16(pf[0][ks], vf, o[0][dt], 0, 0, 0);
                o[1][dt] = __builtin_amdgcn_mfma_f32_16x16x32_bf16(pf[1][ks], vf, o[1][dt], 0, 0, 0);
            }
        __builtin_amdgcn_s_setprio(0);
    }

    for (int qtile = 0; qtile < 2; ++qtile) {
        float inv = 1.0f / l_i[qtile];
        float iB[4];
        for (int r = 0; r < 4; ++r) iB[r] = __shfl(inv, quad * 4 + r, 64);
        for (int r = 0; r < 4; ++r) {
            int qg = q0 + wave * 32 + qtile * 16 + quad * 4 + r;
            u16* yr = Y + ((size_t)((b * T_ + qg) * NH_ + h)) * HD_;
            for (int dt = 0; dt < 8; ++dt)
                yr[dt * 16 + l16] = f2bf(o[qtile][dt][r] * iB[r]);
        }
    }
}

// ---------------------------------------------------------------------------
extern "C" void kernel_launch(void* const* d_in, const int* in_sizes, int n_in,
                              void* d_out, int out_size, void* d_ws, size_t ws_size,
                              hipStream_t stream) {
    const float* x     = (const float*)d_in[0];
    const float* cosb  = (const float*)d_in[1];
    const float* sinb  = (const float*)d_in[2];
    const float* wq    = (const float*)d_in[3];
    const float* wk    = (const float*)d_in[4];
    const float* wv    = (const float*)d_in[5];
    const float* wo    = (const float*)d_in[6];
    const float* wfc   = (const float*)d_in[7];
    const float* wproj = (const float*)d_in[8];

    char* ws = (char*)d_ws;
    size_t off = 0;
    auto alloc = [&](size_t bytes) { char* p = ws + off; off += (bytes + 255) & ~(size_t)255; return p; };

    u16*   wqkvT  = (u16*)alloc((size_t)3072 * C_ * 2);        // rows: q | k | v
    u16*   woT    = (u16*)alloc((size_t)C_ * C_ * 2);
    u16*   wfcT   = (u16*)alloc((size_t)DFF_ * C_ * 2);        // [8192][2048]
    u16*   wprojT = (u16*)alloc((size_t)C_ * DFF_ * 2);        // [2048][8192]
    u16*   hbuf   = (u16*)alloc((size_t)B_ * T_ * C_ * 2);     // h / p0 buffers
    float* x2     = (float*)alloc((size_t)B_ * T_ * C_ * 4);   // post-attn residual
    u16*   ybuf   = (u16*)alloc((size_t)B_ * T_ * C_ * 2);     // attn out / proj p1
    u16*   Vtb    = (u16*)alloc((size_t)B_ * NKV_ * HD_ * T_ * 2);  // V transposed
    // 64MB scratch: qkv temporaries -> wo partial p1 -> ffbuf
    char*  scratch = alloc((size_t)B_ * T_ * DFF_ * 2);
    float* q_tmp  = (float*)scratch;                                     // 32MB
    float* k_tmp  = (float*)(scratch + (size_t)B_ * T_ * C_ * 4);        // 8MB
    u16*   qb     = (u16*)(scratch + (size_t)B_ * T_ * C_ * 4 + (size_t)B_ * T_ * 512 * 4);
    u16*   kb     = (u16*)((char*)qb + (size_t)B_ * T_ * C_ * 2);
    u16*   vb     = (u16*)((char*)kb + (size_t)B_ * T_ * 512 * 2);
    u16*   wop1   = (u16*)scratch;       // wo split-K partial 1 (q_tmp dead by then)
    u16*   ffbuf  = (u16*)scratch;       // [4096][8192] bf16 (after reduce_rms)

    const int M = B_ * T_;   // 4096
    dim3 tb(256);

    // 1+2. weights -> bf16 [N][K] AND h = rmsnorm(x), ONE launch.
    TD6 td;
    td.t[0] = { wq,    wqkvT,                       C_,   C_,   0 };     // 1024
    td.t[1] = { wk,    wqkvT + (size_t)2048 * C_,   C_,   512,  1024 };  // 256
    td.t[2] = { wv,    wqkvT + (size_t)2560 * C_,   C_,   512,  1280 };  // 256
    td.t[3] = { wo,    woT,                         C_,   C_,   1536 };  // 1024
    td.t[4] = { wfc,   wfcT,                        C_,   DFF_, 2560 };  // 4096
    td.t[5] = { wproj, wprojT,                      DFF_, C_,   6656 };  // 4096
    prep_all<<<dim3(TRBLKS_ + M), tb, 0, stream>>>(td, x, hbuf);

    // 3. fused q/k/v projection (N=3072): 12x16 = 192 blocks
    gemm256<4><<<dim3(3072 / 256, M / 256), dim3(512), 0, stream>>>(
        hbuf, wqkvT, q_tmp, k_tmp, vb, M, 3072, C_, C_);

    // 4. RoPE + qk-rmsnorm AND V transpose, ONE launch
    rope_tv<<<dim3(TVB_ + (B_ * T_ * (NH_ + NKV_)) / 4), tb, 0, stream>>>(
        q_tmp, k_tmp, cosb, sinb, qb, kb, vb, Vtb);

    // 5. causal GQA flash attention (512 blocks, 2/CU)
    flash_attn2<<<dim3(512), tb, 0, stream>>>(qb, kb, Vtb, ybuf);

    // 6. wo split-K=2: partials -> hbuf (z=0), wop1 (z=1); 8x16x2 = 256 blocks
    gemm256<5><<<dim3(C_ / 256, M / 256, 2), dim3(512), 0, stream>>>(
        ybuf, woT, hbuf, wop1, nullptr, M, C_, C_ / 2, C_);

    // 7. x2 = x + p0 + p1;  hbuf = rmsnorm(x2)   (p0 aliases hbuf — safe)
    reduce_rms<<<M, tb, 0, stream>>>(x, hbuf, wop1, x2, hbuf);

    // 8. ff = relu(h2 @ w_fc)^2   (ffbuf overwrites scratch after step 7)
    gemm256<2><<<dim3(DFF_ / 256, M / 256), dim3(512), 0, stream>>>(
        hbuf, wfcT, ffbuf, nullptr, nullptr, M, DFF_, C_, C_);

    // 9. proj split-K=2: partials -> hbuf (z=0), ybuf (z=1); 256 blocks
    gemm256<5><<<dim3(C_ / 256, M / 256, 2), dim3(512), 0, stream>>>(
        ffbuf, wprojT, hbuf, ybuf, nullptr, M, C_, DFF_ / 2, DFF_);

    // 10. out = x2 + p0 + p1
    reduce_out<<<dim3((M * C_) / 1024), tb, 0, stream>>>(x2, hbuf, ybuf, (float*)d_out);
}